// Round 3
// baseline (437.405 us; speedup 1.0000x reference)
//
#include <hip/hip_runtime.h>
#include <math.h>

// SSMInterBlock fused kernel (fp32, VALU path).
// Geometry: 12544 sequences, L=4, d_model=96, d_inner=192, N=16, R=6.
// One block = 4 sequences, 256 threads (4 waves), wave w owns seq w in GEMM phases.
// LDS 60,120 B/block -> 2 blocks/CU (__launch_bounds__(256,2)).

#define THREADS 256
#define SEQ_PB  4
#define DM      96     // d_model
#define DE      192    // d_inner
#define NJ      384    // 2*DE (in_proj rows); also 96*4 = out floats per seq
#define NST     16     // d_state
#define RNK     6      // dt_rank
#define NC      38     // RNK + 2*NST
#define XZ_STRIDE 1540 // per-seq pitch in s_xz (1536 + 4: bank stagger, 16B aligned)
#define XD_STRIDE 164  // per-seq pitch of x_dbl (152 + pad)
#define P_W1    97     // W1 tile pitch   (conflict-free b32: bank=(lane+dd)%32)
#define P_XPW   193    // x_proj pitch
#define P_A     20     // A tile pitch
#define P_WO    193    // out_proj pitch

__device__ __forceinline__ float softplus_f(float x) {
    // jax.nn.softplus = max(x,0) + log1p(exp(-|x|))
    return fmaxf(x, 0.f) + log1pf(__expf(-fabsf(x)));
}
__device__ __forceinline__ float silu_f(float x) {
    return x / (1.f + __expf(-x));
}

__global__ __launch_bounds__(THREADS, 2)
void ssm_fused(const float* __restrict__ x,       // [nseq*384] = [seq][dd*4+l]
               const float* __restrict__ w_in,    // [384][96]
               const float* __restrict__ w_xp,    // [38][192]
               const float* __restrict__ w_dt,    // [192][6]
               const float* __restrict__ b_dt,    // [192]
               const float* __restrict__ a_logs,  // [192][16]
               const float* __restrict__ dvec,    // [192]
               const float* __restrict__ gamma_,  // [192]
               const float* __restrict__ beta_,   // [192]
               const float* __restrict__ w_out,   // [96][192]
               float* __restrict__ out)           // [nseq*384] = [seq][dd*4+l]
{
    __shared__ float s_xz[SEQ_PB * XZ_STRIDE];   // 24640 B: u|z, later y, yz
    __shared__ float s_buf2[SEQ_PB * NJ];        // 6144 B: xf; then xdbl + LN stats
    __shared__ float s_tile[NC * P_XPW];         // 29336 B: W1 chunk / xpw / A / Wout chunk

    const int tid  = threadIdx.x;
    const int lane = tid & 63;
    const int wave = tid >> 6;
    const int blk  = blockIdx.x;

    // ---------- P0: load x for 4 seqs (contiguous 1536 floats) ----------
    {
        const float4* xg = (const float4*)x + blk * (SEQ_PB * NJ / 4);
        float4* sf = (float4*)s_buf2;
        for (int i = tid; i < SEQ_PB * NJ / 4; i += THREADS) sf[i] = xg[i];
    }
    __syncthreads();

    // ---------- P-A: xz = silu(xf @ W1^T); u at j<192, z at j>=192 ----------
    for (int jc = 0; jc < NJ; jc += 64) {
        {   // stage W1 rows [jc..jc+64) x 96 -> pitch 97
            const float4* wg = (const float4*)w_in + jc * (DM / 4);
            for (int i = tid; i < 64 * DM / 4; i += THREADS) {
                float4 v = wg[i];
                int flat = i * 4, r = flat / DM, c = flat % DM;
                float* dst = &s_tile[r * P_W1 + c];
                dst[0] = v.x; dst[1] = v.y; dst[2] = v.z; dst[3] = v.w;
            }
        }
        __syncthreads();
        {   // wave = seq; lane = j-jc; 4 accumulators over l
            const int seq = wave;
            const float* xf = &s_buf2[seq * NJ];
            const float* wr = &s_tile[lane * P_W1];
            float a0 = 0.f, a1 = 0.f, a2 = 0.f, a3 = 0.f;
            #pragma unroll 4
            for (int dd = 0; dd < DM; ++dd) {
                float w  = wr[dd];
                float4 xv = *(const float4*)&xf[dd * 4];
                a0 = fmaf(w, xv.x, a0);
                a1 = fmaf(w, xv.y, a1);
                a2 = fmaf(w, xv.z, a2);
                a3 = fmaf(w, xv.w, a3);
            }
            int j = jc + lane;
            float4 sv;
            sv.x = silu_f(a0); sv.y = silu_f(a1); sv.z = silu_f(a2); sv.w = silu_f(a3);
            *(float4*)&s_xz[seq * XZ_STRIDE + j * 4] = sv;
        }
        __syncthreads();
    }

    // ---------- P-B: x_dbl[c][l] = sum_d u[d][l] * xpw[c][d] ----------
    {   // stage xpw [38][192] -> pitch 193
        const float4* wg = (const float4*)w_xp;
        for (int i = tid; i < NC * DE / 4; i += THREADS) {
            float4 v = wg[i];
            int flat = i * 4, r = flat / DE, c = flat % DE;
            float* dst = &s_tile[r * P_XPW + c];
            dst[0] = v.x; dst[1] = v.y; dst[2] = v.z; dst[3] = v.w;
        }
    }
    __syncthreads();
    if (tid < SEQ_PB * NC) {
        int seq = tid & 3, c = tid >> 2;
        const float* wr = &s_tile[c * P_XPW];
        const float* uz = &s_xz[seq * XZ_STRIDE];
        float a0 = 0.f, a1 = 0.f, a2 = 0.f, a3 = 0.f;
        #pragma unroll 4
        for (int d = 0; d < DE; ++d) {
            float w  = wr[d];
            float4 u = *(const float4*)&uz[d * 4];
            a0 = fmaf(w, u.x, a0);
            a1 = fmaf(w, u.y, a1);
            a2 = fmaf(w, u.z, a2);
            a3 = fmaf(w, u.w, a3);
        }
        float4 r4 = make_float4(a0, a1, a2, a3);
        *(float4*)&s_buf2[seq * XD_STRIDE + c * 4] = r4;
    }
    __syncthreads();
    // stage A = -exp(A_logs) -> pitch 20 (overwrites xpw region)
    for (int i = tid; i < DE * NST; i += THREADS) {
        int d = i >> 4, n = i & 15;
        s_tile[d * P_A + n] = -__expf(a_logs[i]);
    }
    __syncthreads();

    // ---------- P-C: delta + selective scan; y overwrites u in place ----------
    #pragma unroll
    for (int rr = 0; rr < 3; ++rr) {
        int p = tid + rr * THREADS;          // 768 (seq,d) pairs
        int seq = p & 3, d = p >> 2;
        float4 u4 = *(const float4*)&s_xz[seq * XZ_STRIDE + d * 4];
        const float* xd = &s_buf2[seq * XD_STRIDE];

        // delta[l] = softplus(sum_r dts[r][l]*w_dt[d][r] + b_dt[d])
        const float* dtr = &w_dt[d * RNK];
        float d0 = 0.f, d1 = 0.f, d2 = 0.f, d3 = 0.f;
        #pragma unroll
        for (int r = 0; r < RNK; ++r) {
            float w  = dtr[r];
            float4 t = *(const float4*)&xd[r * 4];
            d0 = fmaf(w, t.x, d0);
            d1 = fmaf(w, t.y, d1);
            d2 = fmaf(w, t.z, d2);
            d3 = fmaf(w, t.w, d3);
        }
        float bias = b_dt[d];
        float del[4];
        del[0] = softplus_f(d0 + bias);
        del[1] = softplus_f(d1 + bias);
        del[2] = softplus_f(d2 + bias);
        del[3] = softplus_f(d3 + bias);

        // A row (precomputed -exp)
        float aa[NST];
        #pragma unroll
        for (int k = 0; k < 4; ++k) {
            float4 av = *(const float4*)&s_tile[d * P_A + 4 * k];
            aa[4*k+0] = av.x; aa[4*k+1] = av.y; aa[4*k+2] = av.z; aa[4*k+3] = av.w;
        }

        float uarr[4] = {u4.x, u4.y, u4.z, u4.w};
        float h[NST];
        #pragma unroll
        for (int n = 0; n < NST; ++n) h[n] = 0.f;
        const float* xb = xd + RNK * 4;           // B at c=6..21
        const float* xc = xd + (RNK + NST) * 4;   // C at c=22..37
        float Dd = dvec[d];
        float yv[4];
        #pragma unroll
        for (int l = 0; l < 4; ++l) {
            float dl = del[l];
            float du = dl * uarr[l];
            float y = 0.f;
            #pragma unroll
            for (int n = 0; n < NST; ++n) {
                float dA = __expf(dl * aa[n]);
                float hn = fmaf(du, xb[n * 4 + l], dA * h[n]);
                h[n] = hn;
                y = fmaf(hn, xc[n * 4 + l], y);
            }
            yv[l] = fmaf(Dd, uarr[l], y);
        }
        *(float4*)&s_xz[seq * XZ_STRIDE + d * 4] = make_float4(yv[0], yv[1], yv[2], yv[3]);
    }
    __syncthreads();

    // ---------- P-LN: per (seq,l) mean/rstd over De=192 ----------
    {
        int g = tid >> 4;        // 0..15 = seq*4 + l
        int i = tid & 15;
        int seq = g >> 2, l = g & 3;
        float s = 0.f, ss = 0.f;
        #pragma unroll
        for (int k = 0; k < DE / 16; ++k) {
            int d = i + k * 16;
            float v = s_xz[seq * XZ_STRIDE + d * 4 + l];
            s += v;
            ss = fmaf(v, v, ss);
        }
        #pragma unroll
        for (int off = 1; off < 16; off <<= 1) {
            s  += __shfl_xor(s,  off, 16);
            ss += __shfl_xor(ss, off, 16);
        }
        if (i == 0) {
            float mu  = s * (1.f / DE);
            float var = ss * (1.f / DE) - mu * mu;
            s_buf2[656 + g] = mu;                       // mu[seq][l]
            s_buf2[672 + g] = rsqrtf(var + 1e-5f);      // rstd[seq][l]
        }
    }
    __syncthreads();

    // ---------- P-LN2: yz = ((y-mu)*rstd*gamma + beta) * z, in place ----------
    #pragma unroll
    for (int rr = 0; rr < 3; ++rr) {
        int p = tid + rr * THREADS;
        int seq = p & 3, d = p >> 2;
        float4 y4  = *(const float4*)&s_xz[seq * XZ_STRIDE + d * 4];
        float4 z4  = *(const float4*)&s_xz[seq * XZ_STRIDE + (DE + d) * 4];
        float4 mu4 = *(const float4*)&s_buf2[656 + seq * 4];
        float4 rs4 = *(const float4*)&s_buf2[672 + seq * 4];
        float ga = gamma_[d], be = beta_[d];
        float4 o;
        o.x = fmaf((y4.x - mu4.x) * rs4.x, ga, be) * z4.x;
        o.y = fmaf((y4.y - mu4.y) * rs4.y, ga, be) * z4.y;
        o.z = fmaf((y4.z - mu4.z) * rs4.z, ga, be) * z4.z;
        o.w = fmaf((y4.w - mu4.w) * rs4.w, ga, be) * z4.w;
        *(float4*)&s_xz[seq * XZ_STRIDE + d * 4] = o;
    }
    __syncthreads();

    // ---------- P-D: out[l][dd] = sum_d yz[l][d] * w_out[dd][d] ----------
    for (int dc = 0; dc < DM; dc += 32) {
        {   // stage w_out rows [dc..dc+32) x 192 -> pitch 193 (A region dead)
            const float4* wg = (const float4*)w_out + dc * (DE / 4);
            for (int i = tid; i < 32 * DE / 4; i += THREADS) {
                float4 v = wg[i];
                int flat = i * 4, r = flat / DE, c = flat % DE;
                float* dst = &s_tile[r * P_WO + c];
                dst[0] = v.x; dst[1] = v.y; dst[2] = v.z; dst[3] = v.w;
            }
        }
        __syncthreads();
        {
            int seq = tid & 3, ddl = (tid >> 2) & 31, lh = tid >> 7; // full 256-cover
            const float* wr = &s_tile[ddl * P_WO];
            const float* yz = &s_xz[seq * XZ_STRIDE + lh * 2];
            float a0 = 0.f, a1 = 0.f;
            #pragma unroll 4
            for (int d = 0; d < DE; ++d) {
                float w = wr[d];
                float2 y2 = *(const float2*)&yz[d * 4];
                a0 = fmaf(w, y2.x, a0);
                a1 = fmaf(w, y2.y, a1);
            }
            float2 o2 = make_float2(a0, a1);
            *(float2*)&out[blk * (SEQ_PB * NJ) + seq * NJ + (dc + ddl) * 4 + lh * 2] = o2;
        }
        __syncthreads();
    }
}

extern "C" void kernel_launch(void* const* d_in, const int* in_sizes, int n_in,
                              void* d_out, int out_size, void* d_ws, size_t ws_size,
                              hipStream_t stream) {
    (void)n_in; (void)d_ws; (void)ws_size; (void)out_size;
    int nseq = in_sizes[0] / NJ;            // 12544 = 4*56*56
    int grid = nseq / SEQ_PB;               // 3136 blocks
    if (grid < 1) grid = 1;
    ssm_fused<<<grid, THREADS, 0, stream>>>(
        (const float*)d_in[0],  // x
        (const float*)d_in[1],  // in_proj_w
        (const float*)d_in[2],  // x_proj_weight
        (const float*)d_in[3],  // dt_projs_weight
        (const float*)d_in[4],  // dt_projs_bias
        (const float*)d_in[5],  // A_logs
        (const float*)d_in[6],  // Ds
        (const float*)d_in[7],  // ln_gamma
        (const float*)d_in[8],  // ln_beta
        (const float*)d_in[9],  // out_proj_w
        (float*)d_out);
}

// Round 4
// 402.361 us; speedup vs baseline: 1.0871x; 1.0871x over previous
//
#include <hip/hip_runtime.h>
#include <math.h>

// SSMInterBlock fused v2: DS-pipe drain.
// R3 showed 405 us with ~87K DS-pipe cycles/block (matches wall time): every wave
// re-read all weights through LDS scalar reads. v2 moves weights to coalesced
// global (VMEM pipe, L1/L2-hot via d_ws transposes) and x to scalar loads
// (wave-uniform readfirstlane pointer); LDS only for u/z/x_dbl/y handoffs.
// LDS 27.4 KB, __launch_bounds__(256,4) -> 4 blocks/CU (was 2).

#define THREADS 256
#define SEQ_PB  4
#define DM      96
#define DE      192
#define NJ      384
#define NST     16
#define RNK     6
#define NC      38
#define XZS     1540   // per-seq pitch in s_xz (floats)
#define XDS     164    // per-seq pitch of x_dbl (floats)

// d_ws float offsets
#define OFF_WT1  0                      // [96][384]: wt1[dd][j] = w_in[j][dd]
#define OFF_XPW  36864                  // [192][40]: xpwT[d][c] = w_xp[c][d]
#define OFF_NA   (36864 + 7680)         // [192][16]: -exp(A_logs)
#define OFF_WO   (36864 + 7680 + 3072)  // [192][96]: wout[d][dd] = w_out[dd][d]
#define WS_FLOATS (OFF_WO + 18432)      // 66,048 floats = 264 KB

__device__ __forceinline__ float softplus_f(float x) {
    return fmaxf(x, 0.f) + log1pf(__expf(-fabsf(x)));
}
__device__ __forceinline__ float silu_f(float x) {
    return x / (1.f + __expf(-x));
}

__global__ void prep_weights(const float* __restrict__ w_in,
                             const float* __restrict__ w_xp,
                             const float* __restrict__ a_logs,
                             const float* __restrict__ w_out,
                             float* __restrict__ ws) {
    int t0 = blockIdx.x * blockDim.x + threadIdx.x;
    int stride = gridDim.x * blockDim.x;
    for (int t = t0; t < DM * NJ; t += stride) {          // W1^T
        int dd = t / NJ, j = t % NJ;
        ws[OFF_WT1 + t] = w_in[j * DM + dd];
    }
    for (int t = t0; t < DE * NC; t += stride) {          // xpw^T (pitch 40)
        int d = t / NC, c = t % NC;
        ws[OFF_XPW + d * 40 + c] = w_xp[c * DE + d];
    }
    for (int t = t0; t < DE * NST; t += stride)           // -exp(A_logs)
        ws[OFF_NA + t] = -__expf(a_logs[t]);
    for (int t = t0; t < DE * DM; t += stride) {          // Wout^T
        int d = t / DM, dd = t % DM;
        ws[OFF_WO + t] = w_out[dd * DE + d];
    }
}

__global__ __launch_bounds__(THREADS, 4)
void ssm_fused2(const float* __restrict__ x,       // [nseq][384] = [seq][d][l]
                const float* __restrict__ w_dt,    // [192][6]
                const float* __restrict__ b_dt,    // [192]
                const float* __restrict__ dvec,    // [192]
                const float* __restrict__ gamma_,  // [192]
                const float* __restrict__ beta_,   // [192]
                const float* __restrict__ ws,      // transposed weights
                float* __restrict__ out)           // [nseq][384] = [seq][dd][l]
{
    __shared__ float s_xz[SEQ_PB * XZS];   // 24,640 B: u|z, then y, then yz
    __shared__ float s_xd[SEQ_PB * XDS];   //  2,624 B: x_dbl
    __shared__ float s_st[32];             //    128 B: LN mu/rstd

    const int tid  = threadIdx.x;
    const int lane = tid & 63;
    const int blk  = blockIdx.x;
    const int wv   = __builtin_amdgcn_readfirstlane(tid >> 6);  // wave id = seq

    // ---------- P-A: xz = silu(x @ W1^T). wave=seq; lane+m cover j=m*64+lane.
    // x via wave-uniform pointer -> scalar loads; W1^T coalesced global; no DS reads.
    {
        const float4* xs4 = (const float4*)(x + ((size_t)blk * SEQ_PB + wv) * NJ);
        const float* wt1 = ws + OFF_WT1;
        float acc[6][4];
        #pragma unroll
        for (int m = 0; m < 6; ++m) {
            acc[m][0] = 0.f; acc[m][1] = 0.f; acc[m][2] = 0.f; acc[m][3] = 0.f;
        }
        for (int dds = 0; dds < DM; dds += 8) {
            float4 xv[8];
            #pragma unroll
            for (int i = 0; i < 8; ++i) xv[i] = xs4[dds + i];   // uniform -> s_load
            #pragma unroll
            for (int i = 0; i < 8; ++i) {
                const float* wrow = wt1 + (dds + i) * NJ + lane;
                #pragma unroll
                for (int m = 0; m < 6; ++m) {
                    float w = wrow[m * 64];
                    acc[m][0] = fmaf(w, xv[i].x, acc[m][0]);
                    acc[m][1] = fmaf(w, xv[i].y, acc[m][1]);
                    acc[m][2] = fmaf(w, xv[i].z, acc[m][2]);
                    acc[m][3] = fmaf(w, xv[i].w, acc[m][3]);
                }
            }
        }
        #pragma unroll
        for (int m = 0; m < 6; ++m) {
            int j = m * 64 + lane;
            float4 sv;
            sv.x = silu_f(acc[m][0]); sv.y = silu_f(acc[m][1]);
            sv.z = silu_f(acc[m][2]); sv.w = silu_f(acc[m][3]);
            *(float4*)&s_xz[wv * XZS + j * 4] = sv;   // contiguous b128, full BW
        }
    }
    __syncthreads();

    // ---------- P-B: x_dbl[c][l] = sum_d u[d][l] * xpw[c][d]
    if (tid < SEQ_PB * NC) {
        int seq = tid & 3, c = tid >> 2;
        const float* wc = ws + OFF_XPW + c;           // element (d,c) at d*40+c
        const float* uz = &s_xz[seq * XZS];
        float a0 = 0.f, a1 = 0.f, a2 = 0.f, a3 = 0.f;
        for (int d = 0; d < DE; ++d) {
            float w  = wc[d * 40];
            float4 u = *(const float4*)&uz[d * 4];
            a0 = fmaf(w, u.x, a0); a1 = fmaf(w, u.y, a1);
            a2 = fmaf(w, u.z, a2); a3 = fmaf(w, u.w, a3);
        }
        *(float4*)&s_xd[seq * XDS + c * 4] = make_float4(a0, a1, a2, a3);
    }
    __syncthreads();

    // ---------- P-C: delta + selective scan (n outer, h scalar); y in place
    #pragma unroll
    for (int rr = 0; rr < 3; ++rr) {
        int p = tid + rr * THREADS;
        int seq = p & 3, d = p >> 2;
        float4 u4 = *(const float4*)&s_xz[seq * XZS + d * 4];
        const float* xd = &s_xd[seq * XDS];

        const float2* wdt2 = (const float2*)(w_dt + d * RNK);  // 24B-aligned
        float2 wp0 = wdt2[0], wp1 = wdt2[1], wp2 = wdt2[2];
        float wr6[6] = {wp0.x, wp0.y, wp1.x, wp1.y, wp2.x, wp2.y};
        float d0 = 0.f, d1 = 0.f, d2 = 0.f, d3 = 0.f;
        #pragma unroll
        for (int r = 0; r < RNK; ++r) {
            float w  = wr6[r];
            float4 t = *(const float4*)&xd[r * 4];
            d0 = fmaf(w, t.x, d0); d1 = fmaf(w, t.y, d1);
            d2 = fmaf(w, t.z, d2); d3 = fmaf(w, t.w, d3);
        }
        float bias = b_dt[d];
        float dl0 = softplus_f(d0 + bias), dl1 = softplus_f(d1 + bias);
        float dl2 = softplus_f(d2 + bias), dl3 = softplus_f(d3 + bias);
        float du0 = dl0 * u4.x, du1 = dl1 * u4.y;
        float du2 = dl2 * u4.z, du3 = dl3 * u4.w;

        const float* nA = ws + OFF_NA + d * NST;
        float y0 = 0.f, y1 = 0.f, y2 = 0.f, y3 = 0.f;
        #pragma unroll
        for (int n = 0; n < NST; ++n) {
            float an = nA[n];
            float4 bn = *(const float4*)&xd[(RNK + n) * 4];
            float4 cn = *(const float4*)&xd[(RNK + NST + n) * 4];
            float h = du0 * bn.x;                        // l=0: exp(.)*0 + du*B
            y0 = fmaf(h, cn.x, y0);
            h = fmaf(du1, bn.y, __expf(dl1 * an) * h);   // l=1
            y1 = fmaf(h, cn.y, y1);
            h = fmaf(du2, bn.z, __expf(dl2 * an) * h);   // l=2
            y2 = fmaf(h, cn.z, y2);
            h = fmaf(du3, bn.w, __expf(dl3 * an) * h);   // l=3
            y3 = fmaf(h, cn.w, y3);
        }
        float Dd = dvec[d];
        float4 yo;
        yo.x = fmaf(Dd, u4.x, y0); yo.y = fmaf(Dd, u4.y, y1);
        yo.z = fmaf(Dd, u4.z, y2); yo.w = fmaf(Dd, u4.w, y3);
        *(float4*)&s_xz[seq * XZS + d * 4] = yo;
    }
    __syncthreads();

    // ---------- P-LN: per (seq,l) mean/rstd over De=192
    {
        int g = tid >> 4, i = tid & 15;
        int seq = g >> 2, l = g & 3;
        float s = 0.f, ss = 0.f;
        #pragma unroll
        for (int k = 0; k < DE / 16; ++k) {
            float v = s_xz[seq * XZS + (i + k * 16) * 4 + l];
            s += v; ss = fmaf(v, v, ss);
        }
        #pragma unroll
        for (int off = 1; off < 16; off <<= 1) {
            s  += __shfl_xor(s,  off, 16);
            ss += __shfl_xor(ss, off, 16);
        }
        if (i == 0) {
            float mu  = s * (1.f / DE);
            float var = ss * (1.f / DE) - mu * mu;
            s_st[g]      = mu;
            s_st[16 + g] = rsqrtf(var + 1e-5f);
        }
    }
    __syncthreads();

    // ---------- P-LN2: yz = ((y-mu)*rstd*gamma + beta) * z, in place
    #pragma unroll
    for (int rr = 0; rr < 3; ++rr) {
        int p = tid + rr * THREADS;
        int seq = p & 3, d = p >> 2;
        float4 y4  = *(const float4*)&s_xz[seq * XZS + d * 4];
        float4 z4  = *(const float4*)&s_xz[seq * XZS + (DE + d) * 4];
        float4 mu4 = *(const float4*)&s_st[seq * 4];
        float4 rs4 = *(const float4*)&s_st[16 + seq * 4];
        float ga = gamma_[d], be = beta_[d];
        float4 o;
        o.x = fmaf((y4.x - mu4.x) * rs4.x, ga, be) * z4.x;
        o.y = fmaf((y4.y - mu4.y) * rs4.y, ga, be) * z4.y;
        o.z = fmaf((y4.z - mu4.z) * rs4.z, ga, be) * z4.z;
        o.w = fmaf((y4.w - mu4.w) * rs4.w, ga, be) * z4.w;
        *(float4*)&s_xz[seq * XZS + d * 4] = o;
    }
    __syncthreads();

    // ---------- P-D: out[dd][l] = sum_d yz[d][l] * wout[dd][d]; wave=seq
    {
        const int dd1 = lane;              // 0..63
        const int dd2 = 64 + (lane & 31);  // 64..95 (lanes>=32 duplicate, masked store)
        const float* wo  = ws + OFF_WO;
        const float* yzp = &s_xz[wv * XZS];
        float a1_[4] = {0.f, 0.f, 0.f, 0.f};
        float a2_[4] = {0.f, 0.f, 0.f, 0.f};
        #pragma unroll 4
        for (int d = 0; d < DE; ++d) {
            float4 yz = *(const float4*)&yzp[d * 4];   // single-address b128 broadcast
            float w1 = wo[d * DM + dd1];               // coalesced global
            float w2 = wo[d * DM + dd2];
            a1_[0] = fmaf(w1, yz.x, a1_[0]); a1_[1] = fmaf(w1, yz.y, a1_[1]);
            a1_[2] = fmaf(w1, yz.z, a1_[2]); a1_[3] = fmaf(w1, yz.w, a1_[3]);
            a2_[0] = fmaf(w2, yz.x, a2_[0]); a2_[1] = fmaf(w2, yz.y, a2_[1]);
            a2_[2] = fmaf(w2, yz.z, a2_[2]); a2_[3] = fmaf(w2, yz.w, a2_[3]);
        }
        float* ob = out + (size_t)blk * (SEQ_PB * NJ) + wv * NJ;
        *(float4*)&ob[dd1 * 4] = make_float4(a1_[0], a1_[1], a1_[2], a1_[3]);
        if (lane < 32)
            *(float4*)&ob[dd2 * 4] = make_float4(a2_[0], a2_[1], a2_[2], a2_[3]);
    }
}

extern "C" void kernel_launch(void* const* d_in, const int* in_sizes, int n_in,
                              void* d_out, int out_size, void* d_ws, size_t ws_size,
                              hipStream_t stream) {
    (void)n_in; (void)ws_size; (void)out_size;
    int nseq = in_sizes[0] / NJ;            // 12544 = 4*56*56
    int grid = nseq / SEQ_PB;               // 3136 blocks
    if (grid < 1) grid = 1;
    float* ws = (float*)d_ws;               // needs 264 KB

    prep_weights<<<64, THREADS, 0, stream>>>(
        (const float*)d_in[1],  // in_proj_w
        (const float*)d_in[2],  // x_proj_weight
        (const float*)d_in[5],  // A_logs
        (const float*)d_in[9],  // out_proj_w
        ws);

    ssm_fused2<<<grid, THREADS, 0, stream>>>(
        (const float*)d_in[0],  // x
        (const float*)d_in[3],  // dt_projs_weight
        (const float*)d_in[4],  // dt_projs_bias
        (const float*)d_in[6],  // Ds
        (const float*)d_in[7],  // ln_gamma
        (const float*)d_in[8],  // ln_beta
        ws,
        (float*)d_out);
}